// Round 4
// baseline (635.967 us; speedup 1.0000x reference)
//
#include <hip/hip_runtime.h>
#include <stdint.h>

// CommNetActor: B=8192, A=64 agents, OBS=128, D=64, NACT=32
//
// v5 = v4 with fused_kernel de-staged:
//  - sA and sW LDS tiles DELETED. A-fragments read directly from O (global,
//    read-once, f2b-converted in-register); B-fragments read directly from
//    the prepped weight tables (16KB/layer, L1-resident per CU).
//  - LDS drops 45.5KB -> 10.4KB: occupancy cap 3 -> 6+ blocks/CU
//    (__launch_bounds__(256,6)).
//  - Comm semantics byte-identical to proven v1/v4: sH wave-private rows,
//    sPart->sS cross-wave reduce guarded by the same two __syncthreads per
//    layer, same f2b epilogue, same output layout.
//  - prep_kernel / dec_kernel unchanged from v4 (proven).
//
// Math folding: comm layer  H' = Hcat @ W + b,  Hcat=[H_i, (S-H_i)/64]
//   = [H_i | S/64] @ [Wtop - Wbot/64 ; Wbot] + b     (K=128 MFMA, bias in acc init)

#define BATCHN 8192
#define NAGENT 64
#define OBSD   128
#define DD     64
#define NACT   32

typedef __attribute__((ext_vector_type(8))) short short8;   // 8 bf16 (4 VGPRs)
typedef __attribute__((ext_vector_type(4))) float floatx4;  // MFMA acc

__device__ __forceinline__ unsigned short f2b(float f) {
    // fp32 -> bf16 round-to-nearest-even
    union { float f; uint32_t u; } v; v.f = f;
    uint32_t r = v.u + 0x7FFFu + ((v.u >> 16) & 1u);
    return (unsigned short)(r >> 16);
}

// ---- ws layout (byte offsets; ws treated as ushort*) ----
#define OFF_WENC 0                       // WencT  [64 n][128 k] bf16 = 16384 B
#define OFF_WCAT 16384                   // WcatT  [4 l][64 n][128 k] bf16 = 65536 B
#define OFF_WDEC 81920                   // WdecT  [32 n][4096 k] bf16 = 262144 B
#define OFF_H4   344064                  // H4     [8192][4096] bf16 = 67108864 B

// ---------------- prep: transpose + bf16-convert weights ----------------
__global__ __launch_bounds__(256) void prep_kernel(
    const float* __restrict__ Wenc,
    const float* __restrict__ W1, const float* __restrict__ W2,
    const float* __restrict__ W3, const float* __restrict__ W4,
    const float* __restrict__ Wdec,
    unsigned short* __restrict__ ws)
{
    int tid = blockIdx.x * 256 + threadIdx.x;   // grid covers exactly 172032
    if (tid < 8192) {
        int n = tid >> 7, k = tid & 127;
        ws[OFF_WENC/2 + n*128 + k] = f2b(Wenc[k*64 + n]);
    } else if (tid < 5*8192) {
        int l = (tid - 8192) >> 13;
        int e = (tid - 8192) & 8191;
        int n = e >> 7, k = e & 127;
        const float* W = (l==0) ? W1 : (l==1) ? W2 : (l==2) ? W3 : W4;
        float v = W[k*64 + n];                       // k<64: Wtop[k][n], k>=64: Wbot[k-64][n]
        if (k < 64) v -= W[(k+64)*64 + n] * (1.0f/64.0f);
        ws[OFF_WCAT/2 + l*8192 + n*128 + k] = f2b(v);
    } else {
        int e = tid - 5*8192;                        // 0..131071
        int n = e >> 12, k = e & 4095;
        ws[OFF_WDEC/2 + n*4096 + k] = f2b(Wdec[k*32 + n]);
    }
}

// ---------------- fused encoder + 4 comm layers ----------------
// 1 block = 1 sample. 256 thr = 4 waves, wave w owns rows [16w,16w+16).
// No operand staging: A from O/global (encoder) or sH (wave-private LDS),
// B from global weight tables (L1-hot).
__global__ __launch_bounds__(256, 6) void fused_kernel(
    const float* __restrict__ O,
    const unsigned short* __restrict__ WencT,
    const unsigned short* __restrict__ WcatT,
    const float* __restrict__ b_enc,
    const float* __restrict__ b1, const float* __restrict__ b2,
    const float* __restrict__ b3, const float* __restrict__ b4,
    unsigned short* __restrict__ H4out)
{
    __shared__ __align__(16) unsigned short sH[64*72];    // H (64x64), pad 8
    __shared__ __align__(16) unsigned short sS[64];       // S/64 bf16
    __shared__ float sPart[4][64];                        // per-wave column partials

    const int t = threadIdx.x;
    const int b = blockIdx.x;
    const int lane = t & 63;
    const int w = t >> 6;
    const int m = lane & 15;
    const int q = lane >> 4;

    floatx4 acc[4];

    // ---- encoder: H0 = sigmoid(O @ Wenc + b_enc), K=128 ----
    #pragma unroll
    for (int nt = 0; nt < 4; nt++) {
        float bias = b_enc[nt*16 + m];
        acc[nt] = (floatx4){bias, bias, bias, bias};
    }
    {
        const float* Ob = O + (size_t)b * (NAGENT*OBSD) + (w*16 + m)*OBSD + q*8;
        #pragma unroll
        for (int s = 0; s < 4; s++) {
            float4 f0 = *(const float4*)(Ob + s*32);
            float4 f1 = *(const float4*)(Ob + s*32 + 4);
            union { short8 s8; unsigned short u[8]; } ua;
            ua.u[0] = f2b(f0.x); ua.u[1] = f2b(f0.y);
            ua.u[2] = f2b(f0.z); ua.u[3] = f2b(f0.w);
            ua.u[4] = f2b(f1.x); ua.u[5] = f2b(f1.y);
            ua.u[6] = f2b(f1.z); ua.u[7] = f2b(f1.w);
            short8 a = ua.s8;
            #pragma unroll
            for (int nt = 0; nt < 4; nt++) {
                short8 bb = *(const short8*)(WencT + (nt*16 + m)*128 + s*32 + q*8);
                acc[nt] = __builtin_amdgcn_mfma_f32_16x16x32_bf16(a, bb, acc[nt], 0, 0, 0);
            }
        }
    }
    #pragma unroll
    for (int nt = 0; nt < 4; nt++)
        #pragma unroll
        for (int r = 0; r < 4; r++)
            acc[nt][r] = 1.0f / (1.0f + __expf(-acc[nt][r]));

    // encoder epilogue: column sums (for S) + store H0 bf16
    #pragma unroll
    for (int nt = 0; nt < 4; nt++) {
        float s = acc[nt][0] + acc[nt][1] + acc[nt][2] + acc[nt][3];
        s += __shfl_xor(s, 16, 64);
        s += __shfl_xor(s, 32, 64);
        if (q == 0) sPart[w][nt*16 + m] = s;
        #pragma unroll
        for (int r = 0; r < 4; r++)
            sH[(w*16 + q*4 + r)*72 + nt*16 + m] = f2b(acc[nt][r]);
    }

    // ---- 4 comm layers ----
    const float* bs[4] = {b1, b2, b3, b4};
    #pragma unroll
    for (int l = 0; l < 4; l++) {
        __syncthreads();   // sPart (and prior-layer sH/sS traffic) settled
        if (t < 64)
            sS[t] = f2b((sPart[0][t] + sPart[1][t] + sPart[2][t] + sPart[3][t]) * (1.0f/64.0f));
        __syncthreads();   // sS visible to all

        const unsigned short* Wl = WcatT + l*8192;
        const float* bl = bs[l];
        #pragma unroll
        for (int nt = 0; nt < 4; nt++) {
            float bias = bl[nt*16 + m];
            acc[nt] = (floatx4){bias, bias, bias, bias};
        }
        // k = 0..63 from H rows (wave-private LDS)
        #pragma unroll
        for (int s = 0; s < 2; s++) {
            short8 a = *(const short8*)&sH[(w*16 + m)*72 + s*32 + q*8];
            #pragma unroll
            for (int nt = 0; nt < 4; nt++) {
                short8 bb = *(const short8*)(Wl + (nt*16 + m)*128 + s*32 + q*8);
                acc[nt] = __builtin_amdgcn_mfma_f32_16x16x32_bf16(a, bb, acc[nt], 0, 0, 0);
            }
        }
        // k = 64..127: A rows are all S/64 (LDS broadcast)
        #pragma unroll
        for (int s = 0; s < 2; s++) {
            short8 a = *(const short8*)&sS[s*32 + q*8];
            #pragma unroll
            for (int nt = 0; nt < 4; nt++) {
                short8 bb = *(const short8*)(Wl + (nt*16 + m)*128 + (s+2)*32 + q*8);
                acc[nt] = __builtin_amdgcn_mfma_f32_16x16x32_bf16(a, bb, acc[nt], 0, 0, 0);
            }
        }

        if (l < 3) {
            #pragma unroll
            for (int nt = 0; nt < 4; nt++) {
                float s = acc[nt][0] + acc[nt][1] + acc[nt][2] + acc[nt][3];
                s += __shfl_xor(s, 16, 64);
                s += __shfl_xor(s, 32, 64);
                if (q == 0) sPart[w][nt*16 + m] = s;
                #pragma unroll
                for (int r = 0; r < 4; r++)
                    sH[(w*16 + q*4 + r)*72 + nt*16 + m] = f2b(acc[nt][r]);
            }
        } else {
            unsigned short* Hb = H4out + (size_t)b * 4096;
            #pragma unroll
            for (int nt = 0; nt < 4; nt++)
                #pragma unroll
                for (int r = 0; r < 4; r++)
                    Hb[(w*16 + q*4 + r)*64 + nt*16 + m] = f2b(acc[nt][r]);
        }
    }
}

// ---------------- decoder: out = Hf @ Wdec + b_dec (atomic-free) ----------------
// M=8192, N=32, K=4096. 512 blocks x 512 thr: block owns 16 rows; 8 waves
// split K into 512-chunks; LDS tree-reduce; direct store (no memset needed).
__global__ __launch_bounds__(512) void dec_kernel(
    const unsigned short* __restrict__ Hf,     // [8192][4096] bf16
    const unsigned short* __restrict__ WdecT,  // [32][4096] bf16
    const float* __restrict__ b_dec,
    float* __restrict__ out)                   // [8192][32] fp32
{
    __shared__ float red[8][16][34];           // +2 pad: conflict-free
    const int t = threadIdx.x;
    const int wv = t >> 6, lane = t & 63;
    const int m = lane & 15, q = lane >> 4;
    const int rb = blockIdx.x;                 // rows [rb*16, rb*16+16)
    const int kc = wv;                         // K chunk [kc*512, kc*512+512)

    const unsigned short* aP  = Hf    + (size_t)(rb*16 + m)*4096 + kc*512 + q*8;
    const unsigned short* bP0 = WdecT + (size_t)m*4096        + kc*512 + q*8;
    const unsigned short* bP1 = WdecT + (size_t)(16 + m)*4096 + kc*512 + q*8;

    floatx4 a0 = {0.f, 0.f, 0.f, 0.f}, a1 = {0.f, 0.f, 0.f, 0.f};
    #pragma unroll 4
    for (int s = 0; s < 16; s++) {
        short8 av  = *(const short8*)(aP  + s*32);
        short8 b0v = *(const short8*)(bP0 + s*32);
        short8 b1v = *(const short8*)(bP1 + s*32);
        a0 = __builtin_amdgcn_mfma_f32_16x16x32_bf16(av, b0v, a0, 0, 0, 0);
        a1 = __builtin_amdgcn_mfma_f32_16x16x32_bf16(av, b1v, a1, 0, 0, 0);
    }
    #pragma unroll
    for (int r = 0; r < 4; r++) {
        red[wv][q*4 + r][m]      = a0[r];
        red[wv][q*4 + r][16 + m] = a1[r];
    }
    __syncthreads();
    const int row = t >> 5, col = t & 31;      // 512 threads -> 16x32 outputs
    float sum = b_dec[col];
    #pragma unroll
    for (int i = 0; i < 8; i++)
        sum += red[i][row][col];
    out[(size_t)(rb*16 + row)*32 + col] = sum;
}

extern "C" void kernel_launch(void* const* d_in, const int* in_sizes, int n_in,
                              void* d_out, int out_size, void* d_ws, size_t ws_size,
                              hipStream_t stream)
{
    const float* O    = (const float*)d_in[0];
    const float* Wenc = (const float*)d_in[1];
    const float* benc = (const float*)d_in[2];
    const float* W1   = (const float*)d_in[3];
    const float* b1   = (const float*)d_in[4];
    const float* W2   = (const float*)d_in[5];
    const float* b2   = (const float*)d_in[6];
    const float* W3   = (const float*)d_in[7];
    const float* b3   = (const float*)d_in[8];
    const float* W4   = (const float*)d_in[9];
    const float* b4   = (const float*)d_in[10];
    const float* Wdec = (const float*)d_in[11];
    const float* bdec = (const float*)d_in[12];
    float* out = (float*)d_out;
    unsigned short* ws = (unsigned short*)d_ws;

    prep_kernel<<<672, 256, 0, stream>>>(Wenc, W1, W2, W3, W4, Wdec, ws);
    fused_kernel<<<BATCHN, 256, 0, stream>>>(O, ws + OFF_WENC/2, ws + OFF_WCAT/2,
                                             benc, b1, b2, b3, b4, ws + OFF_H4/2);
    dec_kernel<<<512, 512, 0, stream>>>(ws + OFF_H4/2, ws + OFF_WDEC/2, bdec, out);
}

// Round 5
// 433.793 us; speedup vs baseline: 1.4661x; 1.4661x over previous
//
#include <hip/hip_runtime.h>
#include <stdint.h>

// CommNetActor: B=8192, A=64 agents, OBS=128, D=64, NACT=32
//
// v6 = v4 (proven 453us) with three targeted fused_kernel changes:
//  1. sA deleted: encoder A-fragments read from O directly (in-register f2b)
//     -- this exact path ran correct in v5. B stays LDS-staged (v5 proved
//     per-wave global B-fetch serializes on load latency).
//  2. sW is LINEAR 16KB, XOR-swizzled at the source: prep writes the weight
//     image with k_img = c2 ^ ((n&7)<<3), fused stages it with a plain
//     linear uint4 copy and applies the same XOR on fragment reads ->
//     conflict-optimal ds_read_b128 on both sides.
//  3. LDS 45.5KB -> 26.4KB -> 6 blocks/CU (__launch_bounds__(256,6)).
// Everything else (sH pad-72, sPart/sS exchange, 2 barriers/layer, epilogue,
// prep structure, dec_kernel, H4/WdecT layouts) byte-identical to v4.
//
// Math folding: comm layer  H' = Hcat @ W + b,  Hcat=[H_i, (S-H_i)/64]
//   = [H_i | S/64] @ [Wtop - Wbot/64 ; Wbot] + b     (K=128 MFMA, bias in acc init)

#define BATCHN 8192
#define NAGENT 64
#define OBSD   128
#define DD     64
#define NACT   32

typedef __attribute__((ext_vector_type(8))) short short8;   // 8 bf16 (4 VGPRs)
typedef __attribute__((ext_vector_type(4))) float floatx4;  // MFMA acc

__device__ __forceinline__ unsigned short f2b(float f) {
    // fp32 -> bf16 round-to-nearest-even
    union { float f; uint32_t u; } v; v.f = f;
    uint32_t r = v.u + 0x7FFFu + ((v.u >> 16) & 1u);
    return (unsigned short)(r >> 16);
}

// ---- ws layout (byte offsets; ws treated as ushort*) ----
#define OFF_WENC 0                       // WencT image [64 n][128 c2] bf16 (c2 = k ^ ((n&7)<<3))
#define OFF_WCAT 16384                   // WcatT image [4 l][64 n][128 c2] bf16 (same swizzle)
#define OFF_WDEC 81920                   // WdecT  [32 n][4096 k] bf16 = 262144 B (plain)
#define OFF_H4   344064                  // H4     [8192][4096] bf16 (plain)

// ---------------- prep: transpose + bf16-convert weights ----------------
// WencT/WcatT are stored in the exact linear image fused_kernel stages into
// LDS: image ushort index i = n*128 + c2 holds element k = c2 ^ ((n&7)<<3).
__global__ __launch_bounds__(256) void prep_kernel(
    const float* __restrict__ Wenc,
    const float* __restrict__ W1, const float* __restrict__ W2,
    const float* __restrict__ W3, const float* __restrict__ W4,
    const float* __restrict__ Wdec,
    unsigned short* __restrict__ ws)
{
    int tid = blockIdx.x * 256 + threadIdx.x;   // grid covers exactly 172032
    if (tid < 8192) {
        int n = tid >> 7, c2 = tid & 127;
        int k = c2 ^ ((n & 7) << 3);            // swizzled image index
        ws[OFF_WENC/2 + n*128 + c2] = f2b(Wenc[k*64 + n]);
    } else if (tid < 5*8192) {
        int l = (tid - 8192) >> 13;
        int e = (tid - 8192) & 8191;
        int n = e >> 7, c2 = e & 127;
        int k = c2 ^ ((n & 7) << 3);            // XOR hits k bits 3..5 only: halves preserved
        const float* W = (l==0) ? W1 : (l==1) ? W2 : (l==2) ? W3 : W4;
        float v = W[k*64 + n];                  // k<64: Wtop[k][n], k>=64: Wbot[k-64][n]
        if (k < 64) v -= W[(k+64)*64 + n] * (1.0f/64.0f);
        ws[OFF_WCAT/2 + l*8192 + n*128 + c2] = f2b(v);
    } else {
        int e = tid - 5*8192;                   // 0..131071
        int n = e >> 12, k = e & 4095;
        ws[OFF_WDEC/2 + n*4096 + k] = f2b(Wdec[k*32 + n]);
    }
}

// ---------------- fused encoder + 4 comm layers ----------------
// 1 block = 1 sample. 256 thr = 4 waves, wave w owns rows [16w,16w+16).
// B from linear swizzled sW (staged cooperatively); encoder A from O direct.
__global__ __launch_bounds__(256, 6) void fused_kernel(
    const float* __restrict__ O,
    const unsigned short* __restrict__ WencT,
    const unsigned short* __restrict__ WcatT,
    const float* __restrict__ b_enc,
    const float* __restrict__ b1, const float* __restrict__ b2,
    const float* __restrict__ b3, const float* __restrict__ b4,
    unsigned short* __restrict__ H4out)
{
    __shared__ __align__(16) unsigned short sW[64*128];   // 16KB linear, swizzled image
    __shared__ __align__(16) unsigned short sH[64*72];    // H (64x64), pad 8 (proven)
    __shared__ __align__(16) unsigned short sS[64];       // S/64 bf16
    __shared__ float sPart[4][64];                        // per-wave column partials

    const int t = threadIdx.x;
    const int b = blockIdx.x;
    const int lane = t & 63;
    const int w = t >> 6;
    const int m = lane & 15;
    const int q = lane >> 4;
    const int mx = (m & 7) << 3;                // ushort-index XOR for B reads

    // stage WencT image (linear 16KB copy)
    #pragma unroll
    for (int i = 0; i < 4; i++) {
        int c = t + i*256;
        *(uint4*)&sW[c*8] = *(const uint4*)(WencT + c*8);
    }
    __syncthreads();

    floatx4 acc[4];

    // ---- encoder: H0 = sigmoid(O @ Wenc + b_enc), K=128 ----
    #pragma unroll
    for (int nt = 0; nt < 4; nt++) {
        float bias = b_enc[nt*16 + m];
        acc[nt] = (floatx4){bias, bias, bias, bias};
    }
    {
        const float* Ob = O + (size_t)b * (NAGENT*OBSD) + (w*16 + m)*OBSD + q*8;
        #pragma unroll
        for (int s = 0; s < 4; s++) {
            float4 f0 = *(const float4*)(Ob + s*32);
            float4 f1 = *(const float4*)(Ob + s*32 + 4);
            union { short8 s8; unsigned short u[8]; } ua;
            ua.u[0] = f2b(f0.x); ua.u[1] = f2b(f0.y);
            ua.u[2] = f2b(f0.z); ua.u[3] = f2b(f0.w);
            ua.u[4] = f2b(f1.x); ua.u[5] = f2b(f1.y);
            ua.u[6] = f2b(f1.z); ua.u[7] = f2b(f1.w);
            short8 a = ua.s8;
            #pragma unroll
            for (int nt = 0; nt < 4; nt++) {
                short8 bb = *(const short8*)&sW[(nt*16 + m)*128 + ((s*32 + q*8) ^ mx)];
                acc[nt] = __builtin_amdgcn_mfma_f32_16x16x32_bf16(a, bb, acc[nt], 0, 0, 0);
            }
        }
    }
    #pragma unroll
    for (int nt = 0; nt < 4; nt++)
        #pragma unroll
        for (int r = 0; r < 4; r++)
            acc[nt][r] = 1.0f / (1.0f + __expf(-acc[nt][r]));

    // encoder epilogue: column sums (for S) + store H0 bf16
    #pragma unroll
    for (int nt = 0; nt < 4; nt++) {
        float s = acc[nt][0] + acc[nt][1] + acc[nt][2] + acc[nt][3];
        s += __shfl_xor(s, 16, 64);
        s += __shfl_xor(s, 32, 64);
        if (q == 0) sPart[w][nt*16 + m] = s;
        #pragma unroll
        for (int r = 0; r < 4; r++)
            sH[(w*16 + q*4 + r)*72 + nt*16 + m] = f2b(acc[nt][r]);
    }

    // ---- 4 comm layers ----
    const float* bs[4] = {b1, b2, b3, b4};
    #pragma unroll
    for (int l = 0; l < 4; l++) {
        __syncthreads();   // old sW reads done; sPart writes visible
        #pragma unroll
        for (int i = 0; i < 4; i++) {
            int c = t + i*256;
            *(uint4*)&sW[c*8] = *(const uint4*)(WcatT + l*8192 + c*8);
        }
        if (t < 64)
            sS[t] = f2b((sPart[0][t] + sPart[1][t] + sPart[2][t] + sPart[3][t]) * (1.0f/64.0f));
        __syncthreads();

        const float* bl = bs[l];
        #pragma unroll
        for (int nt = 0; nt < 4; nt++) {
            float bias = bl[nt*16 + m];
            acc[nt] = (floatx4){bias, bias, bias, bias};
        }
        // k = 0..63 from H rows (wave-private sH, pad-72)
        #pragma unroll
        for (int s = 0; s < 2; s++) {
            short8 a = *(const short8*)&sH[(w*16 + m)*72 + s*32 + q*8];
            #pragma unroll
            for (int nt = 0; nt < 4; nt++) {
                short8 bb = *(const short8*)&sW[(nt*16 + m)*128 + ((s*32 + q*8) ^ mx)];
                acc[nt] = __builtin_amdgcn_mfma_f32_16x16x32_bf16(a, bb, acc[nt], 0, 0, 0);
            }
        }
        // k = 64..127: A rows are all S/64 (LDS broadcast)
        #pragma unroll
        for (int s = 0; s < 2; s++) {
            short8 a = *(const short8*)&sS[s*32 + q*8];
            #pragma unroll
            for (int nt = 0; nt < 4; nt++) {
                short8 bb = *(const short8*)&sW[(nt*16 + m)*128 + (((s+2)*32 + q*8) ^ mx)];
                acc[nt] = __builtin_amdgcn_mfma_f32_16x16x32_bf16(a, bb, acc[nt], 0, 0, 0);
            }
        }

        if (l < 3) {
            #pragma unroll
            for (int nt = 0; nt < 4; nt++) {
                float s = acc[nt][0] + acc[nt][1] + acc[nt][2] + acc[nt][3];
                s += __shfl_xor(s, 16, 64);
                s += __shfl_xor(s, 32, 64);
                if (q == 0) sPart[w][nt*16 + m] = s;
                #pragma unroll
                for (int r = 0; r < 4; r++)
                    sH[(w*16 + q*4 + r)*72 + nt*16 + m] = f2b(acc[nt][r]);
            }
        } else {
            unsigned short* Hb = H4out + (size_t)b * 4096;
            #pragma unroll
            for (int nt = 0; nt < 4; nt++)
                #pragma unroll
                for (int r = 0; r < 4; r++)
                    Hb[(w*16 + q*4 + r)*64 + nt*16 + m] = f2b(acc[nt][r]);
        }
    }
}

// ---------------- decoder: out = Hf @ Wdec + b_dec (atomic-free) ----------------
// M=8192, N=32, K=4096. 512 blocks x 512 thr: block owns 16 rows; 8 waves
// split K into 512-chunks; LDS tree-reduce; direct store (no memset needed).
__global__ __launch_bounds__(512) void dec_kernel(
    const unsigned short* __restrict__ Hf,     // [8192][4096] bf16
    const unsigned short* __restrict__ WdecT,  // [32][4096] bf16
    const float* __restrict__ b_dec,
    float* __restrict__ out)                   // [8192][32] fp32
{
    __shared__ float red[8][16][34];           // +2 pad: conflict-free
    const int t = threadIdx.x;
    const int wv = t >> 6, lane = t & 63;
    const int m = lane & 15, q = lane >> 4;
    const int rb = blockIdx.x;                 // rows [rb*16, rb*16+16)
    const int kc = wv;                         // K chunk [kc*512, kc*512+512)

    const unsigned short* aP  = Hf    + (size_t)(rb*16 + m)*4096 + kc*512 + q*8;
    const unsigned short* bP0 = WdecT + (size_t)m*4096        + kc*512 + q*8;
    const unsigned short* bP1 = WdecT + (size_t)(16 + m)*4096 + kc*512 + q*8;

    floatx4 a0 = {0.f, 0.f, 0.f, 0.f}, a1 = {0.f, 0.f, 0.f, 0.f};
    #pragma unroll 4
    for (int s = 0; s < 16; s++) {
        short8 av  = *(const short8*)(aP  + s*32);
        short8 b0v = *(const short8*)(bP0 + s*32);
        short8 b1v = *(const short8*)(bP1 + s*32);
        a0 = __builtin_amdgcn_mfma_f32_16x16x32_bf16(av, b0v, a0, 0, 0, 0);
        a1 = __builtin_amdgcn_mfma_f32_16x16x32_bf16(av, b1v, a1, 0, 0, 0);
    }
    #pragma unroll
    for (int r = 0; r < 4; r++) {
        red[wv][q*4 + r][m]      = a0[r];
        red[wv][q*4 + r][16 + m] = a1[r];
    }
    __syncthreads();
    const int row = t >> 5, col = t & 31;      // 512 threads -> 16x32 outputs
    float sum = b_dec[col];
    #pragma unroll
    for (int i = 0; i < 8; i++)
        sum += red[i][row][col];
    out[(size_t)(rb*16 + row)*32 + col] = sum;
}

extern "C" void kernel_launch(void* const* d_in, const int* in_sizes, int n_in,
                              void* d_out, int out_size, void* d_ws, size_t ws_size,
                              hipStream_t stream)
{
    const float* O    = (const float*)d_in[0];
    const float* Wenc = (const float*)d_in[1];
    const float* benc = (const float*)d_in[2];
    const float* W1   = (const float*)d_in[3];
    const float* b1   = (const float*)d_in[4];
    const float* W2   = (const float*)d_in[5];
    const float* b2   = (const float*)d_in[6];
    const float* W3   = (const float*)d_in[7];
    const float* b3   = (const float*)d_in[8];
    const float* W4   = (const float*)d_in[9];
    const float* b4   = (const float*)d_in[10];
    const float* Wdec = (const float*)d_in[11];
    const float* bdec = (const float*)d_in[12];
    float* out = (float*)d_out;
    unsigned short* ws = (unsigned short*)d_ws;

    prep_kernel<<<672, 256, 0, stream>>>(Wenc, W1, W2, W3, W4, Wdec, ws);
    fused_kernel<<<BATCHN, 256, 0, stream>>>(O, ws + OFF_WENC/2, ws + OFF_WCAT/2,
                                             benc, b1, b2, b3, b4, ws + OFF_H4/2);
    dec_kernel<<<512, 512, 0, stream>>>(ws + OFF_H4/2, ws + OFF_WDEC/2, bdec, out);
}

// Round 6
// 433.554 us; speedup vs baseline: 1.4669x; 1.0006x over previous
//
#include <hip/hip_runtime.h>
#include <stdint.h>

// CommNetActor: B=8192, A=64 agents, OBS=128, D=64, NACT=32
//
// v7 = v6 (proven 434us) with two structural fused_kernel changes:
//  1. 2 samples/block (512 thr, 8 waves): waves 0-3 = sample A, 4-7 = sample
//     B, SHARING one 16KB sW stage -> per-sample staging and barrier cost
//     halved. LDS 37.1KB -> 4 blocks/CU = 32 waves/CU (occupancy ceiling),
//     __launch_bounds__(512,8) caps VGPR at 64 (v6 used 36).
//  2. T14 async-stage split on sW: next layer's weight loads issued into
//     registers right after the MFMA-phase barrier (hidden under MFMA +
//     epilogue), committed regs->LDS after the next barrier. Register
//     data-dependence makes the overlap reorder-safe.
// Micro: sigmoid uses __builtin_amdgcn_rcpf (validated in v5).
// prep/dec and all layouts byte-identical to v6.
//
// Math folding: comm layer  H' = Hcat @ W + b,  Hcat=[H_i, (S-H_i)/64]
//   = [H_i | S/64] @ [Wtop - Wbot/64 ; Wbot] + b     (K=128 MFMA, bias in acc init)

#define BATCHN 8192
#define NAGENT 64
#define OBSD   128
#define DD     64
#define NACT   32

typedef __attribute__((ext_vector_type(8))) short short8;   // 8 bf16 (4 VGPRs)
typedef __attribute__((ext_vector_type(4))) float floatx4;  // MFMA acc

__device__ __forceinline__ unsigned short f2b(float f) {
    // fp32 -> bf16 round-to-nearest-even
    union { float f; uint32_t u; } v; v.f = f;
    uint32_t r = v.u + 0x7FFFu + ((v.u >> 16) & 1u);
    return (unsigned short)(r >> 16);
}

// ---- ws layout (byte offsets; ws treated as ushort*) ----
#define OFF_WENC 0                       // WencT image [64 n][128 c2] bf16 (c2 = k ^ ((n&7)<<3))
#define OFF_WCAT 16384                   // WcatT image [4 l][64 n][128 c2] bf16 (same swizzle)
#define OFF_WDEC 81920                   // WdecT  [32 n][4096 k] bf16 = 262144 B (plain)
#define OFF_H4   344064                  // H4     [8192][4096] bf16 (plain)

// ---------------- prep: transpose + bf16-convert weights ----------------
// WencT/WcatT are stored in the exact linear image fused_kernel stages into
// LDS: image ushort index i = n*128 + c2 holds element k = c2 ^ ((n&7)<<3).
__global__ __launch_bounds__(256) void prep_kernel(
    const float* __restrict__ Wenc,
    const float* __restrict__ W1, const float* __restrict__ W2,
    const float* __restrict__ W3, const float* __restrict__ W4,
    const float* __restrict__ Wdec,
    unsigned short* __restrict__ ws)
{
    int tid = blockIdx.x * 256 + threadIdx.x;   // grid covers exactly 172032
    if (tid < 8192) {
        int n = tid >> 7, c2 = tid & 127;
        int k = c2 ^ ((n & 7) << 3);            // swizzled image index
        ws[OFF_WENC/2 + n*128 + c2] = f2b(Wenc[k*64 + n]);
    } else if (tid < 5*8192) {
        int l = (tid - 8192) >> 13;
        int e = (tid - 8192) & 8191;
        int n = e >> 7, c2 = e & 127;
        int k = c2 ^ ((n & 7) << 3);            // XOR hits k bits 3..5 only: halves preserved
        const float* W = (l==0) ? W1 : (l==1) ? W2 : (l==2) ? W3 : W4;
        float v = W[k*64 + n];                  // k<64: Wtop[k][n], k>=64: Wbot[k-64][n]
        if (k < 64) v -= W[(k+64)*64 + n] * (1.0f/64.0f);
        ws[OFF_WCAT/2 + l*8192 + n*128 + c2] = f2b(v);
    } else {
        int e = tid - 5*8192;                   // 0..131071
        int n = e >> 12, k = e & 4095;
        ws[OFF_WDEC/2 + n*4096 + k] = f2b(Wdec[k*32 + n]);
    }
}

// ---------------- fused encoder + 4 comm layers ----------------
// 1 block = 2 samples. 512 thr = 8 waves; wave w: sample h=w>>2, rows
// [16*(w&3), 16*(w&3)+16). One shared sW stage; T14 prefetch of next layer.
__global__ __launch_bounds__(512, 8) void fused_kernel(
    const float* __restrict__ O,
    const unsigned short* __restrict__ WencT,
    const unsigned short* __restrict__ WcatT,
    const float* __restrict__ b_enc,
    const float* __restrict__ b1, const float* __restrict__ b2,
    const float* __restrict__ b3, const float* __restrict__ b4,
    unsigned short* __restrict__ H4out)
{
    __shared__ __align__(16) unsigned short sW[64*128];    // 16KB linear, swizzled image
    __shared__ __align__(16) unsigned short sH[2][64*72];  // per-sample H, pad 8
    __shared__ __align__(16) unsigned short sS[2][64];     // per-sample S/64 bf16
    __shared__ float sPart[2][4][64];                      // per-sample per-wave partials

    const int t = threadIdx.x;
    const int lane = t & 63;
    const int w = t >> 6;          // 0..7
    const int h = w >> 2;          // sample half within block
    const int wp = w & 3;          // wave within sample
    const int m = lane & 15;
    const int q = lane >> 4;
    const int mx = (m & 7) << 3;   // ushort-index XOR for B reads
    const int samp = blockIdx.x * 2 + h;

    // stage WencT image (linear 16KB copy, 512 thr x 2 uint4)
    #pragma unroll
    for (int i = 0; i < 2; i++) {
        int c = t + i*512;
        *(uint4*)&sW[c*8] = *(const uint4*)(WencT + c*8);
    }
    __syncthreads();

    floatx4 acc[4];

    // ---- encoder: H0 = sigmoid(O @ Wenc + b_enc), K=128 ----
    #pragma unroll
    for (int nt = 0; nt < 4; nt++) {
        float bias = b_enc[nt*16 + m];
        acc[nt] = (floatx4){bias, bias, bias, bias};
    }
    {
        const float* Ob = O + (size_t)samp * (NAGENT*OBSD) + (wp*16 + m)*OBSD + q*8;
        #pragma unroll
        for (int s = 0; s < 4; s++) {
            float4 f0 = *(const float4*)(Ob + s*32);
            float4 f1 = *(const float4*)(Ob + s*32 + 4);
            union { short8 s8; unsigned short u[8]; } ua;
            ua.u[0] = f2b(f0.x); ua.u[1] = f2b(f0.y);
            ua.u[2] = f2b(f0.z); ua.u[3] = f2b(f0.w);
            ua.u[4] = f2b(f1.x); ua.u[5] = f2b(f1.y);
            ua.u[6] = f2b(f1.z); ua.u[7] = f2b(f1.w);
            short8 a = ua.s8;
            #pragma unroll
            for (int nt = 0; nt < 4; nt++) {
                short8 bb = *(const short8*)&sW[(nt*16 + m)*128 + ((s*32 + q*8) ^ mx)];
                acc[nt] = __builtin_amdgcn_mfma_f32_16x16x32_bf16(a, bb, acc[nt], 0, 0, 0);
            }
        }
    }

    // T14: prefetch layer-0 weight image into regs (hidden under epilogue)
    uint4 wr0 = *(const uint4*)(WcatT + t*8);
    uint4 wr1 = *(const uint4*)(WcatT + (t + 512)*8);

    #pragma unroll
    for (int nt = 0; nt < 4; nt++)
        #pragma unroll
        for (int r = 0; r < 4; r++)
            acc[nt][r] = __builtin_amdgcn_rcpf(1.0f + __expf(-acc[nt][r]));

    // encoder epilogue: column sums (for S) + store H0 bf16
    #pragma unroll
    for (int nt = 0; nt < 4; nt++) {
        float s = acc[nt][0] + acc[nt][1] + acc[nt][2] + acc[nt][3];
        s += __shfl_xor(s, 16, 64);
        s += __shfl_xor(s, 32, 64);
        if (q == 0) sPart[h][wp][nt*16 + m] = s;
        #pragma unroll
        for (int r = 0; r < 4; r++)
            sH[h][(wp*16 + q*4 + r)*72 + nt*16 + m] = f2b(acc[nt][r]);
    }

    // ---- 4 comm layers ----
    const float* bs[4] = {b1, b2, b3, b4};
    #pragma unroll
    for (int l = 0; l < 4; l++) {
        __syncthreads();   // old sW reads done; sPart writes visible
        *(uint4*)&sW[t*8]         = wr0;   // commit prefetched layer-l image
        *(uint4*)&sW[(t+512)*8]   = wr1;
        if (t < 128) {
            int hh = t >> 6, i = t & 63;
            sS[hh][i] = f2b((sPart[hh][0][i] + sPart[hh][1][i] +
                             sPart[hh][2][i] + sPart[hh][3][i]) * (1.0f/64.0f));
        }
        __syncthreads();   // sW/sS visible

        if (l < 3) {       // T14: issue next layer's loads under this MFMA phase
            wr0 = *(const uint4*)(WcatT + (l+1)*8192 + t*8);
            wr1 = *(const uint4*)(WcatT + (l+1)*8192 + (t + 512)*8);
        }

        const float* bl = bs[l];
        #pragma unroll
        for (int nt = 0; nt < 4; nt++) {
            float bias = bl[nt*16 + m];
            acc[nt] = (floatx4){bias, bias, bias, bias};
        }
        // k = 0..63 from H rows (per-sample sH, pad-72)
        #pragma unroll
        for (int s = 0; s < 2; s++) {
            short8 a = *(const short8*)&sH[h][(wp*16 + m)*72 + s*32 + q*8];
            #pragma unroll
            for (int nt = 0; nt < 4; nt++) {
                short8 bb = *(const short8*)&sW[(nt*16 + m)*128 + ((s*32 + q*8) ^ mx)];
                acc[nt] = __builtin_amdgcn_mfma_f32_16x16x32_bf16(a, bb, acc[nt], 0, 0, 0);
            }
        }
        // k = 64..127: A rows are all S/64 (LDS broadcast)
        #pragma unroll
        for (int s = 0; s < 2; s++) {
            short8 a = *(const short8*)&sS[h][s*32 + q*8];
            #pragma unroll
            for (int nt = 0; nt < 4; nt++) {
                short8 bb = *(const short8*)&sW[(nt*16 + m)*128 + (((s+2)*32 + q*8) ^ mx)];
                acc[nt] = __builtin_amdgcn_mfma_f32_16x16x32_bf16(a, bb, acc[nt], 0, 0, 0);
            }
        }

        if (l < 3) {
            #pragma unroll
            for (int nt = 0; nt < 4; nt++) {
                float s = acc[nt][0] + acc[nt][1] + acc[nt][2] + acc[nt][3];
                s += __shfl_xor(s, 16, 64);
                s += __shfl_xor(s, 32, 64);
                if (q == 0) sPart[h][wp][nt*16 + m] = s;
                #pragma unroll
                for (int r = 0; r < 4; r++)
                    sH[h][(wp*16 + q*4 + r)*72 + nt*16 + m] = f2b(acc[nt][r]);
            }
        } else {
            unsigned short* Hb = H4out + (size_t)samp * 4096;
            #pragma unroll
            for (int nt = 0; nt < 4; nt++)
                #pragma unroll
                for (int r = 0; r < 4; r++)
                    Hb[(wp*16 + q*4 + r)*64 + nt*16 + m] = f2b(acc[nt][r]);
        }
    }
}

// ---------------- decoder: out = Hf @ Wdec + b_dec (atomic-free) ----------------
// M=8192, N=32, K=4096. 512 blocks x 512 thr: block owns 16 rows; 8 waves
// split K into 512-chunks; LDS tree-reduce; direct store (no memset needed).
__global__ __launch_bounds__(512) void dec_kernel(
    const unsigned short* __restrict__ Hf,     // [8192][4096] bf16
    const unsigned short* __restrict__ WdecT,  // [32][4096] bf16
    const float* __restrict__ b_dec,
    float* __restrict__ out)                   // [8192][32] fp32
{
    __shared__ float red[8][16][34];           // +2 pad: conflict-free
    const int t = threadIdx.x;
    const int wv = t >> 6, lane = t & 63;
    const int m = lane & 15, q = lane >> 4;
    const int rb = blockIdx.x;                 // rows [rb*16, rb*16+16)
    const int kc = wv;                         // K chunk [kc*512, kc*512+512)

    const unsigned short* aP  = Hf    + (size_t)(rb*16 + m)*4096 + kc*512 + q*8;
    const unsigned short* bP0 = WdecT + (size_t)m*4096        + kc*512 + q*8;
    const unsigned short* bP1 = WdecT + (size_t)(16 + m)*4096 + kc*512 + q*8;

    floatx4 a0 = {0.f, 0.f, 0.f, 0.f}, a1 = {0.f, 0.f, 0.f, 0.f};
    #pragma unroll 4
    for (int s = 0; s < 16; s++) {
        short8 av  = *(const short8*)(aP  + s*32);
        short8 b0v = *(const short8*)(bP0 + s*32);
        short8 b1v = *(const short8*)(bP1 + s*32);
        a0 = __builtin_amdgcn_mfma_f32_16x16x32_bf16(av, b0v, a0, 0, 0, 0);
        a1 = __builtin_amdgcn_mfma_f32_16x16x32_bf16(av, b1v, a1, 0, 0, 0);
    }
    #pragma unroll
    for (int r = 0; r < 4; r++) {
        red[wv][q*4 + r][m]      = a0[r];
        red[wv][q*4 + r][16 + m] = a1[r];
    }
    __syncthreads();
    const int row = t >> 5, col = t & 31;      // 512 threads -> 16x32 outputs
    float sum = b_dec[col];
    #pragma unroll
    for (int i = 0; i < 8; i++)
        sum += red[i][row][col];
    out[(size_t)(rb*16 + row)*32 + col] = sum;
}

extern "C" void kernel_launch(void* const* d_in, const int* in_sizes, int n_in,
                              void* d_out, int out_size, void* d_ws, size_t ws_size,
                              hipStream_t stream)
{
    const float* O    = (const float*)d_in[0];
    const float* Wenc = (const float*)d_in[1];
    const float* benc = (const float*)d_in[2];
    const float* W1   = (const float*)d_in[3];
    const float* b1   = (const float*)d_in[4];
    const float* W2   = (const float*)d_in[5];
    const float* b2   = (const float*)d_in[6];
    const float* W3   = (const float*)d_in[7];
    const float* b3   = (const float*)d_in[8];
    const float* W4   = (const float*)d_in[9];
    const float* b4   = (const float*)d_in[10];
    const float* Wdec = (const float*)d_in[11];
    const float* bdec = (const float*)d_in[12];
    float* out = (float*)d_out;
    unsigned short* ws = (unsigned short*)d_ws;

    prep_kernel<<<672, 256, 0, stream>>>(Wenc, W1, W2, W3, W4, Wdec, ws);
    fused_kernel<<<BATCHN/2, 512, 0, stream>>>(O, ws + OFF_WENC/2, ws + OFF_WCAT/2,
                                               benc, b1, b2, b3, b4, ws + OFF_H4/2);
    dec_kernel<<<512, 512, 0, stream>>>(ws + OFF_H4/2, ws + OFF_WDEC/2, bdec, out);
}